// Round 1
// baseline (855.809 us; speedup 1.0000x reference)
//
#include <hip/hip_runtime.h>

// Problem constants (from reference): B=32, M=32768, D=128, R=64, W=2R+1=129
#define RB_B 32
#define RB_M 32768
#define RB_D 128
#define RB_W 129
// float4 vectors per row = D/4 = 32; per batch = M*32 = 2^20

__global__ __launch_bounds__(256) void ring_update_kernel(
    const float4* __restrict__ ring,      // (B, M, D) viewed as float4
    const float*  __restrict__ wv,        // (B, D)
    const float*  __restrict__ wts,       // (B, W)
    const float*  __restrict__ erase,     // (B,)
    const float*  __restrict__ wgate,     // (B,)
    const int*    __restrict__ idx,       // (B, W) — idx[b*W+0] == start_b
    float4*       __restrict__ out)       // (B, M, D) viewed as float4
{
    const long long total  = (long long)RB_B * RB_M * (RB_D / 4);  // 33,554,432
    const long long stride = (long long)gridDim.x * blockDim.x;

    for (long long i = (long long)blockIdx.x * blockDim.x + threadIdx.x;
         i < total; i += stride) {
        const int b   = (int)(i >> 20);            // i / (M*D/4)
        const int rem = (int)(i & ((1 << 20) - 1));
        const int m   = rem >> 5;                  // row within batch
        const int dv  = rem & 31;                  // float4 index within row

        float4 v = ring[i];

        const int start = idx[b * RB_W];           // idx[b][0] == start_b
        const int j = (m - start) & (RB_M - 1);    // (m - start) mod M

        if (j < RB_W) {
            const float w     = wts[b * RB_W + j];
            const float scale = 1.0f - erase[b] * w;
            const float gw    = wgate[b] * w;
            const float4 wv4  = ((const float4*)wv)[b * (RB_D / 4) + dv];
            v.x = v.x * scale + gw * wv4.x;
            v.y = v.y * scale + gw * wv4.y;
            v.z = v.z * scale + gw * wv4.z;
            v.w = v.w * scale + gw * wv4.w;
        }
        out[i] = v;
    }
}

extern "C" void kernel_launch(void* const* d_in, const int* in_sizes, int n_in,
                              void* d_out, int out_size, void* d_ws, size_t ws_size,
                              hipStream_t stream) {
    const float4* ring  = (const float4*)d_in[0];
    const float*  wv    = (const float*)d_in[1];
    const float*  wts   = (const float*)d_in[2];
    const float*  ers   = (const float*)d_in[3];
    const float*  wg    = (const float*)d_in[4];
    const int*    idx   = (const int*)d_in[5];
    float4*       out   = (float4*)d_out;

    // 33,554,432 float4 elements; 16384 blocks x 256 threads -> 8 vec4/thread
    const int threads = 256;
    const int blocks  = 16384;
    ring_update_kernel<<<blocks, threads, 0, stream>>>(ring, wv, wts, ers, wg, idx, out);
}